// Round 1
// baseline (356.945 us; speedup 1.0000x reference)
//
#include <hip/hip_runtime.h>

// OrthoLoss: scalar = BCE(y_zt,target) + lambda_od*(KL_t + KL_s) + lambda_e*Entropy(s_zt)
// B=65536, D=128, S=2. Memory-bound: ~257 MB of reads, ~43 us HBM floor.
//
// Inputs (setup_inputs order):
//  0 mean_t (B,D) 1 mean_s (B,D) 2 log_std_t (B,D) 3 log_std_s (B,D)
//  4 y_zt (B,1)   5 s_zt (B,2)   6 s_zs UNUSED     7 z1 UNUSED 8 z2 UNUSED
//  9 target (B,1) 10 noise_pt 11 noise_ps 12 noise_et 13 noise_es (B,D)
//  14 current_step (int scalar)

#define B_SIZE 65536
#define D_SIZE 128
#define FLIP_IDX 13
#define GRID 2048
#define BLOCK 256

// ---- wave reduction helpers -------------------------------------------------
// half-wave (32-lane) butterfly: masks 1..16 never cross the 32-lane boundary,
// so the two 32-lane halves of a wave64 reduce independently (two rows/wave).
__device__ __forceinline__ float half_reduce_sum(float v) {
#pragma unroll
    for (int m = 1; m <= 16; m <<= 1) v += __shfl_xor(v, m, 64);
    return v;
}
__device__ __forceinline__ float half_reduce_max(float v) {
#pragma unroll
    for (int m = 1; m <= 16; m <<= 1) v = fmaxf(v, __shfl_xor(v, m, 64));
    return v;
}
__device__ __forceinline__ float wave_reduce_sum(float v) {
#pragma unroll
    for (int m = 1; m <= 32; m <<= 1) v += __shfl_xor(v, m, 64);
    return v;
}

// Per-(half-wave) row KL contribution: sum_d q*(log q - log p)
//   = S_ep/S_e - (me + log S_e) + (mp + log S_p), q = softmax(e) rowwise.
__device__ __forceinline__ float row_kl(float e0, float e1, float e2, float e3,
                                        float p0, float p1, float p2, float p3) {
    float me = half_reduce_max(fmaxf(fmaxf(e0, e1), fmaxf(e2, e3)));
    float mp = half_reduce_max(fmaxf(fmaxf(p0, p1), fmaxf(p2, p3)));
    float x0 = expf(e0 - me), x1 = expf(e1 - me);
    float x2 = expf(e2 - me), x3 = expf(e3 - me);
    float se  = (x0 + x1) + (x2 + x3);
    float sp  = (expf(p0 - mp) + expf(p1 - mp)) + (expf(p2 - mp) + expf(p3 - mp));
    float sep = x0 * (e0 - p0) + x1 * (e1 - p1) + x2 * (e2 - p2) + x3 * (e3 - p3);
    se  = half_reduce_sum(se);
    sp  = half_reduce_sum(sp);
    sep = half_reduce_sum(sep);
    return sep / se - (me + logf(se)) + (mp + logf(sp));
}

// ---- kernels ----------------------------------------------------------------
__global__ void init_acc(double* acc) {
    if (threadIdx.x < 4) acc[threadIdx.x] = 0.0;
}

__global__ __launch_bounds__(BLOCK, 2) void ortho_main(
    const float* __restrict__ mean_t,   const float* __restrict__ mean_s,
    const float* __restrict__ log_std_t,const float* __restrict__ log_std_s,
    const float* __restrict__ y_zt,     const float* __restrict__ s_zt,
    const float* __restrict__ target,
    const float* __restrict__ noise_pt, const float* __restrict__ noise_ps,
    const float* __restrict__ noise_et, const float* __restrict__ noise_es,
    double* __restrict__ acc)
{
    const int tid   = blockIdx.x * BLOCK + threadIdx.x;
    const int lane  = threadIdx.x & 63;
    const int wid   = threadIdx.x >> 6;                 // wave in block (0..3)
    const int gwave = blockIdx.x * (BLOCK / 64) + wid;  // global wave id
    const int nwave = GRID * (BLOCK / 64);

    const int half  = lane >> 5;        // which row of the pair
    const int l32   = lane & 31;
    const int dbase = l32 * 4;          // 4 consecutive f32 per lane (16B)

    // mean_1 = zeros with [13]=1 (t-prior); mean_2 = ones with [13]=0 (s-prior)
    const float m1_0 = (dbase + 0 == FLIP_IDX) ? 1.f : 0.f;
    const float m1_1 = (dbase + 1 == FLIP_IDX) ? 1.f : 0.f;
    const float m1_2 = (dbase + 2 == FLIP_IDX) ? 1.f : 0.f;
    const float m1_3 = (dbase + 3 == FLIP_IDX) ? 1.f : 0.f;

    float kl_t_acc = 0.f, kl_s_acc = 0.f;

    for (int rp = gwave; rp < (B_SIZE / 2); rp += nwave) {
        const int row = rp * 2 + half;
        const size_t off = (size_t)row * D_SIZE + dbase;

        // ---- t stream: enc from (mean_t, log_std_t, noise_et); prior mean_1+noise_pt
        {
            const float4 mt = *(const float4*)(mean_t    + off);
            const float4 ls = *(const float4*)(log_std_t + off);
            const float4 ne = *(const float4*)(noise_et  + off);
            const float4 np = *(const float4*)(noise_pt  + off);
            const float e0 = mt.x + expf(0.5f * ls.x) * ne.x;
            const float e1 = mt.y + expf(0.5f * ls.y) * ne.y;
            const float e2 = mt.z + expf(0.5f * ls.z) * ne.z;
            const float e3 = mt.w + expf(0.5f * ls.w) * ne.w;
            const float p0 = m1_0 + np.x, p1 = m1_1 + np.y;
            const float p2 = m1_2 + np.z, p3 = m1_3 + np.w;
            const float kl = row_kl(e0, e1, e2, e3, p0, p1, p2, p3);
            if (l32 == 0) kl_t_acc += kl;   // lanes 0 and 32: one per row
        }
        // ---- s stream: enc from (mean_s, log_std_s, noise_es); prior mean_2+noise_ps
        {
            const float4 ms = *(const float4*)(mean_s    + off);
            const float4 ls = *(const float4*)(log_std_s + off);
            const float4 ne = *(const float4*)(noise_es  + off);
            const float4 np = *(const float4*)(noise_ps  + off);
            const float e0 = ms.x + expf(0.5f * ls.x) * ne.x;
            const float e1 = ms.y + expf(0.5f * ls.y) * ne.y;
            const float e2 = ms.z + expf(0.5f * ls.z) * ne.z;
            const float e3 = ms.w + expf(0.5f * ls.w) * ne.w;
            const float p0 = (1.f - m1_0) + np.x, p1 = (1.f - m1_1) + np.y;
            const float p2 = (1.f - m1_2) + np.z, p3 = (1.f - m1_3) + np.w;
            const float kl = row_kl(e0, e1, e2, e3, p0, p1, p2, p3);
            if (l32 == 0) kl_s_acc += kl;
        }
    }

    // ---- small terms: BCE over (B,1) and entropy over (B,2), one b per thread
    float bce_acc = 0.f, ent_acc = 0.f;
    for (int b = tid; b < B_SIZE; b += GRID * BLOCK) {
        const float y = y_zt[b];
        const float t = target[b];
        bce_acc += fmaxf(y, 0.f) - y * t + log1pf(expf(-fabsf(y)));
        const float2 s = *(const float2*)(s_zt + 2 * (size_t)b);
        const float m   = fmaxf(s.x, s.y);
        const float lse = m + logf(expf(s.x - m) + expf(s.y - m));
        const float l0 = s.x - lse, l1 = s.y - lse;
        ent_acc -= expf(l0) * l0 + expf(l1) * l1;
    }

    // ---- block reduce (wave butterfly -> LDS -> thread 0) -> f64 atomics
    __shared__ float sm[4][BLOCK / 64];
    float v0 = wave_reduce_sum(bce_acc);
    float v1 = wave_reduce_sum(ent_acc);
    float v2 = wave_reduce_sum(kl_t_acc);
    float v3 = wave_reduce_sum(kl_s_acc);
    if (lane == 0) { sm[0][wid] = v0; sm[1][wid] = v1; sm[2][wid] = v2; sm[3][wid] = v3; }
    __syncthreads();
    if (threadIdx.x == 0) {
        float t0 = 0.f, t1 = 0.f, t2 = 0.f, t3 = 0.f;
#pragma unroll
        for (int w = 0; w < BLOCK / 64; ++w) {
            t0 += sm[0][w]; t1 += sm[1][w]; t2 += sm[2][w]; t3 += sm[3][w];
        }
        atomicAdd(&acc[0], (double)t0);
        atomicAdd(&acc[1], (double)t1);
        atomicAdd(&acc[2], (double)t2);
        atomicAdd(&acc[3], (double)t3);
    }
}

__global__ void ortho_final(const double* __restrict__ acc,
                            const int* __restrict__ step,
                            float* __restrict__ out)
{
    if (threadIdx.x == 0 && blockIdx.x == 0) {
        const double invB = 1.0 / (double)B_SIZE;
        const double frac = (double)step[0] / 30.0;
        const double lambda_e  = 0.1   * pow(2.0, frac);
        const double lambda_od = 0.036 * pow(1.1, frac);
        const double L_t    = acc[0] * invB;
        const double Loss_e = acc[1] * invB;
        const double L_z    = (acc[2] + acc[3]) * invB;
        out[0] = (float)(L_t + lambda_od * L_z + lambda_e * Loss_e);
    }
}

extern "C" void kernel_launch(void* const* d_in, const int* in_sizes, int n_in,
                              void* d_out, int out_size, void* d_ws, size_t ws_size,
                              hipStream_t stream) {
    const float* mean_t    = (const float*)d_in[0];
    const float* mean_s    = (const float*)d_in[1];
    const float* log_std_t = (const float*)d_in[2];
    const float* log_std_s = (const float*)d_in[3];
    const float* y_zt      = (const float*)d_in[4];
    const float* s_zt      = (const float*)d_in[5];
    // d_in[6] s_zs, d_in[7] z1, d_in[8] z2: unused by the reference
    const float* target    = (const float*)d_in[9];
    const float* noise_pt  = (const float*)d_in[10];
    const float* noise_ps  = (const float*)d_in[11];
    const float* noise_et  = (const float*)d_in[12];
    const float* noise_es  = (const float*)d_in[13];
    const int*   step      = (const int*)d_in[14];

    double* acc = (double*)d_ws;   // 4 accumulators: bce, ent, kl_t, kl_s
    float*  out = (float*)d_out;

    hipLaunchKernelGGL(init_acc, dim3(1), dim3(64), 0, stream, acc);
    hipLaunchKernelGGL(ortho_main, dim3(GRID), dim3(BLOCK), 0, stream,
                       mean_t, mean_s, log_std_t, log_std_s,
                       y_zt, s_zt, target,
                       noise_pt, noise_ps, noise_et, noise_es, acc);
    hipLaunchKernelGGL(ortho_final, dim3(1), dim3(64), 0, stream, acc, step, out);
}

// Round 2
// 305.270 us; speedup vs baseline: 1.1693x; 1.1693x over previous
//
#include <hip/hip_runtime.h>

// OrthoLoss: scalar = BCE(y_zt,target) + lambda_od*(KL_t+KL_s) + lambda_e*Entropy(s_zt)
// B=65536, D=128. Memory-bound target: ~135-257 MB reads -> 25-40 us floor.
//
// Round-2 design (vs round-1 latency-bound 152 us @ 886 GB/s):
//  - 8 lanes per row (8 rows/wave), ONE shot per wave (no loop): 65536 rows
//    = 8192 waves = 2048 blocks x 256 threads exactly.
//  - Fixed exponent shift M=40 instead of data-dependent row max: kills the
//    max-reduce and its dependency; the 3 row sums reduce independently with
//    3-step xor{1,2,4} butterflies (vs 5-step x5 dependent chains before).
//  - Lambdas computed in-kernel from step -> single combined accumulator ->
//    one wave reduce -> one f64 partial per block (no init kernel, no atomics).

#define B_SIZE 65536
#define D_SIZE 128
#define GRID   2048
#define BLOCK  256

__device__ __forceinline__ float red8(float v) {   // sum across 8-lane group
    v += __shfl_xor(v, 1, 64);
    v += __shfl_xor(v, 2, 64);
    v += __shfl_xor(v, 4, 64);
    return v;
}
__device__ __forceinline__ float red64(float v) {  // full-wave sum
#pragma unroll
    for (int m = 1; m <= 32; m <<= 1) v += __shfl_xor(v, m, 64);
    return v;
}

__global__ __launch_bounds__(BLOCK, 4) void ortho_main(
    const float* __restrict__ mean_t,   const float* __restrict__ mean_s,
    const float* __restrict__ log_std_t,const float* __restrict__ log_std_s,
    const float* __restrict__ y_zt,     const float* __restrict__ s_zt,
    const float* __restrict__ target,
    const float* __restrict__ noise_pt, const float* __restrict__ noise_ps,
    const float* __restrict__ noise_et, const float* __restrict__ noise_es,
    const int*  __restrict__ step,
    double* __restrict__ partial)
{
    const int lane = threadIdx.x & 63;
    const int wid  = threadIdx.x >> 6;            // wave in block (0..3)
    const int k    = lane & 7;                    // lane within 8-lane row group
    const int row  = (blockIdx.x * (BLOCK / 64) + wid) * 8 + (lane >> 3);
    const size_t base = (size_t)row * D_SIZE + k * 4;  // +j*32 per chunk

    // lambdas (cheap, uniform; step is a broadcast scalar load)
    const float frac      = (float)step[0] * (1.0f / 30.0f);
    const float lambda_e  = 0.1f   * exp2f(frac);
    const float lambda_od = 0.036f * exp2f(frac * 0.13750352374993502f); // log2(1.1)

    const float pk3 = (k == 3) ? 1.0f : 0.0f;     // element 13 = (k=3, j=0, x=1)

    float comb = 0.0f;

    // ---------------- t stream: enc(mean_t,log_std_t,noise_et) vs prior m1+noise_pt
    {
        float se = 0.f, sp = 0.f, sep = 0.f;
#pragma unroll
        for (int j = 0; j < 4; ++j) {
            const size_t off = base + (size_t)j * 32;
            const float4 mt = *(const float4*)(mean_t    + off);
            const float4 ls = *(const float4*)(log_std_t + off);
            const float4 ne = *(const float4*)(noise_et  + off);
            const float4 np = *(const float4*)(noise_pt  + off);
#define ELEM_T(MX, LX, NX, PX, PM)                          \
            {                                               \
                float e  = fmaf(expf(0.5f * (LX)), (NX), (MX)); \
                float ex = expf(e - 40.0f);                 \
                float p  = (PM) + (PX);                     \
                se += ex; sp += expf(p);                    \
                sep = fmaf(ex, e - p, sep);                 \
            }
            ELEM_T(mt.x, ls.x, ne.x, np.x, 0.0f)
            ELEM_T(mt.y, ls.y, ne.y, np.y, (j == 0 ? pk3 : 0.0f))
            ELEM_T(mt.z, ls.z, ne.z, np.z, 0.0f)
            ELEM_T(mt.w, ls.w, ne.w, np.w, 0.0f)
#undef ELEM_T
        }
        se = red8(se); sp = red8(sp); sep = red8(sep);
        if (k == 0) {
            const float kl = sep / se - (40.0f + logf(se)) + logf(sp);
            comb += lambda_od * kl;
        }
    }

    // ---------------- s stream: enc(mean_s,log_std_s,noise_es) vs prior m2+noise_ps
    {
        float se = 0.f, sp = 0.f, sep = 0.f;
#pragma unroll
        for (int j = 0; j < 4; ++j) {
            const size_t off = base + (size_t)j * 32;
            const float4 ms = *(const float4*)(mean_s    + off);
            const float4 ls = *(const float4*)(log_std_s + off);
            const float4 ne = *(const float4*)(noise_es  + off);
            const float4 np = *(const float4*)(noise_ps  + off);
#define ELEM_S(MX, LX, NX, PX, PM)                          \
            {                                               \
                float e  = fmaf(expf(0.5f * (LX)), (NX), (MX)); \
                float ex = expf(e - 40.0f);                 \
                float p  = (PM) + (PX);                     \
                se += ex; sp += expf(p);                    \
                sep = fmaf(ex, e - p, sep);                 \
            }
            ELEM_S(ms.x, ls.x, ne.x, np.x, 1.0f)
            ELEM_S(ms.y, ls.y, ne.y, np.y, (j == 0 ? 1.0f - pk3 : 1.0f))
            ELEM_S(ms.z, ls.z, ne.z, np.z, 1.0f)
            ELEM_S(ms.w, ls.w, ne.w, np.w, 1.0f)
#undef ELEM_S
        }
        se = red8(se); sp = red8(sp); sep = red8(sep);
        if (k == 0) {
            const float kl = sep / se - (40.0f + logf(se)) + logf(sp);
            comb += lambda_od * kl;
        }
    }

    // ---------------- small terms: 32 rows of BCE + entropy per block
    if (threadIdx.x < 32) {
        const int b = blockIdx.x * 32 + threadIdx.x;
        const float y = y_zt[b];
        const float t = target[b];
        const float bce = fmaxf(y, 0.f) - y * t + log1pf(expf(-fabsf(y)));
        const float2 s = *(const float2*)(s_zt + 2 * (size_t)b);
        const float m   = fmaxf(s.x, s.y);
        const float lse = m + logf(expf(s.x - m) + expf(s.y - m));
        const float l0 = s.x - lse, l1 = s.y - lse;
        const float ent = -(expf(l0) * l0 + expf(l1) * l1);
        comb += bce + lambda_e * ent;
    }

    // ---------------- one reduction for everything -> f64 partial per block
    comb = red64(comb);
    __shared__ float sm[BLOCK / 64];
    if (lane == 0) sm[wid] = comb;
    __syncthreads();
    if (threadIdx.x == 0) {
        float t0 = 0.f;
#pragma unroll
        for (int w = 0; w < BLOCK / 64; ++w) t0 += sm[w];
        partial[blockIdx.x] = (double)t0;
    }
}

__global__ void ortho_final(const double* __restrict__ partial,
                            float* __restrict__ out)
{
    double s = 0.0;
    for (int i = threadIdx.x; i < GRID; i += BLOCK) s += partial[i];
#pragma unroll
    for (int m = 1; m <= 32; m <<= 1) s += __shfl_xor(s, m, 64);
    __shared__ double sm[BLOCK / 64];
    const int lane = threadIdx.x & 63;
    const int wid  = threadIdx.x >> 6;
    if (lane == 0) sm[wid] = s;
    __syncthreads();
    if (threadIdx.x == 0) {
        double tot = 0.0;
#pragma unroll
        for (int w = 0; w < BLOCK / 64; ++w) tot += sm[w];
        out[0] = (float)(tot / (double)B_SIZE);
    }
}

extern "C" void kernel_launch(void* const* d_in, const int* in_sizes, int n_in,
                              void* d_out, int out_size, void* d_ws, size_t ws_size,
                              hipStream_t stream) {
    const float* mean_t    = (const float*)d_in[0];
    const float* mean_s    = (const float*)d_in[1];
    const float* log_std_t = (const float*)d_in[2];
    const float* log_std_s = (const float*)d_in[3];
    const float* y_zt      = (const float*)d_in[4];
    const float* s_zt      = (const float*)d_in[5];
    // d_in[6] s_zs, d_in[7] z1, d_in[8] z2: unused by the reference
    const float* target    = (const float*)d_in[9];
    const float* noise_pt  = (const float*)d_in[10];
    const float* noise_ps  = (const float*)d_in[11];
    const float* noise_et  = (const float*)d_in[12];
    const float* noise_es  = (const float*)d_in[13];
    const int*   step      = (const int*)d_in[14];

    double* partial = (double*)d_ws;   // 2048 doubles, all written every launch
    float*  out     = (float*)d_out;

    hipLaunchKernelGGL(ortho_main, dim3(GRID), dim3(BLOCK), 0, stream,
                       mean_t, mean_s, log_std_t, log_std_s,
                       y_zt, s_zt, target,
                       noise_pt, noise_ps, noise_et, noise_es, step, partial);
    hipLaunchKernelGGL(ortho_final, dim3(1), dim3(BLOCK), 0, stream, partial, out);
}

// Round 3
// 304.750 us; speedup vs baseline: 1.1713x; 1.0017x over previous
//
#include <hip/hip_runtime.h>

// OrthoLoss: scalar = BCE(y_zt,target) + lambda_od*(KL_t+KL_s) + lambda_e*Entropy(s_zt)
// B=65536, D=128. Reads 257 MB (8 arrays of B*D f32); ~131 MB misses to HBM
// (rest L3-hot from the harness restore). Main-kernel floor ~25-40 us.
//
// Round-3 changes (vs round-2: 103.7 us, VGPR=32, VALU 22%, HBM 16% -> latency-bound):
//  - __launch_bounds__(256,4): 128-VGPR cap so the compiler can keep ~16-32
//    float4 loads in flight per wave (round-2's 32-VGPR allocation forced
//    serialized load->waitcnt->use batches; per-wave MLP was ~2 loads).
//  - Both streams interleaved in ONE fully-unrolled j-loop: 8 float4 loads
//    per j, 32 total, all independent -> deep MLP.
//  - Native transcendentals: exp2f/__logf (v_exp_f32/v_log_f32) with constants
//    folded into the exp2 args; kills the libm expf accurate-path overhead and
//    shortens the e -> exp(e-40) -> sep dependency chain.

#define B_SIZE 65536
#define D_SIZE 128
#define GRID   2048
#define BLOCK  256

#define L2E  1.44269504089f           // log2(e)
#define HL2E 0.72134752045f           // 0.5*log2(e)
#define SHIFT_L2E 57.7078016356f      // 40*log2(e)

__device__ __forceinline__ float red8(float v) {   // sum across 8-lane group
    v += __shfl_xor(v, 1, 64);
    v += __shfl_xor(v, 2, 64);
    v += __shfl_xor(v, 4, 64);
    return v;
}
__device__ __forceinline__ float red64(float v) {  // full-wave sum
#pragma unroll
    for (int m = 1; m <= 32; m <<= 1) v += __shfl_xor(v, m, 64);
    return v;
}

__global__ __launch_bounds__(BLOCK, 4) void ortho_main(
    const float* __restrict__ mean_t,   const float* __restrict__ mean_s,
    const float* __restrict__ log_std_t,const float* __restrict__ log_std_s,
    const float* __restrict__ y_zt,     const float* __restrict__ s_zt,
    const float* __restrict__ target,
    const float* __restrict__ noise_pt, const float* __restrict__ noise_ps,
    const float* __restrict__ noise_et, const float* __restrict__ noise_es,
    const int*  __restrict__ step,
    double* __restrict__ partial)
{
    const int lane = threadIdx.x & 63;
    const int wid  = threadIdx.x >> 6;            // wave in block (0..3)
    const int k    = lane & 7;                    // lane within 8-lane row group
    const int row  = (blockIdx.x * (BLOCK / 64) + wid) * 8 + (lane >> 3);
    const int idx  = row * D_SIZE + k * 4;        // fits 32-bit (max 8.4M)

    const float frac      = (float)step[0] * (1.0f / 30.0f);
    const float lambda_e  = 0.1f   * exp2f(frac);
    const float lambda_od = 0.036f * exp2f(frac * 0.13750352374993502f); // log2(1.1)

    const float pk3 = (k == 3) ? 1.0f : 0.0f;     // element 13 = (k=3, j=0, y-slot)

    float se_t = 0.f, sp_t = 0.f, sep_t = 0.f;
    float se_s = 0.f, sp_s = 0.f, sep_s = 0.f;

    // elem macro: e = mean + exp(0.5*ls)*noise ; ex = exp(e-40) ; p = pm+np
    //   se += ex ; sp += exp(p) ; sep += ex*(e-p)
#define ELEM(SE, SP, SEP, MX, LX, NX, PX, PM)                         \
    {                                                                 \
        float e  = fmaf(exp2f((LX) * HL2E), (NX), (MX));              \
        float ex = exp2f(fmaf(e, L2E, -SHIFT_L2E));                   \
        float p  = (PM) + (PX);                                       \
        SE += ex;                                                     \
        SP += exp2f(p * L2E);                                         \
        SEP = fmaf(ex, e - p, SEP);                                   \
    }

#pragma unroll
    for (int j = 0; j < 4; ++j) {
        const int o = idx + j * 32;
        // issue all 8 loads for this j up front (independent; deep MLP)
        const float4 mt  = *(const float4*)(mean_t    + o);
        const float4 lt  = *(const float4*)(log_std_t + o);
        const float4 net = *(const float4*)(noise_et  + o);
        const float4 npt = *(const float4*)(noise_pt  + o);
        const float4 ms  = *(const float4*)(mean_s    + o);
        const float4 ls  = *(const float4*)(log_std_s + o);
        const float4 nes = *(const float4*)(noise_es  + o);
        const float4 nps = *(const float4*)(noise_ps  + o);

        const float pmt = (j == 0) ? pk3 : 0.0f;        // t-prior mean, y-slot
        const float pms = (j == 0) ? 1.0f - pk3 : 1.0f; // s-prior mean, y-slot

        ELEM(se_t, sp_t, sep_t, mt.x, lt.x, net.x, npt.x, 0.0f)
        ELEM(se_t, sp_t, sep_t, mt.y, lt.y, net.y, npt.y, pmt)
        ELEM(se_t, sp_t, sep_t, mt.z, lt.z, net.z, npt.z, 0.0f)
        ELEM(se_t, sp_t, sep_t, mt.w, lt.w, net.w, npt.w, 0.0f)

        ELEM(se_s, sp_s, sep_s, ms.x, ls.x, nes.x, nps.x, 1.0f)
        ELEM(se_s, sp_s, sep_s, ms.y, ls.y, nes.y, nps.y, pms)
        ELEM(se_s, sp_s, sep_s, ms.z, ls.z, nes.z, nps.z, 1.0f)
        ELEM(se_s, sp_s, sep_s, ms.w, ls.w, nes.w, nps.w, 1.0f)
    }
#undef ELEM

    se_t = red8(se_t); sp_t = red8(sp_t); sep_t = red8(sep_t);
    se_s = red8(se_s); sp_s = red8(sp_s); sep_s = red8(sep_s);

    float comb = 0.0f;
    if (k == 0) {
        const float kl_t = sep_t / se_t - 40.0f + (__logf(sp_t) - __logf(se_t));
        const float kl_s = sep_s / se_s - 40.0f + (__logf(sp_s) - __logf(se_s));
        comb = lambda_od * (kl_t + kl_s);
    }

    // ---------------- small terms: 32 rows of BCE + entropy per block
    if (threadIdx.x < 32) {
        const int b = blockIdx.x * 32 + threadIdx.x;
        const float y = y_zt[b];
        const float t = target[b];
        const float bce = fmaxf(y, 0.f) - y * t + __logf(1.0f + exp2f(-fabsf(y) * L2E));
        const float2 s = *(const float2*)(s_zt + 2 * (size_t)b);
        const float m   = fmaxf(s.x, s.y);
        const float lse = m + __logf(exp2f((s.x - m) * L2E) + exp2f((s.y - m) * L2E));
        const float l0 = s.x - lse, l1 = s.y - lse;
        const float ent = -(exp2f(l0 * L2E) * l0 + exp2f(l1 * L2E) * l1);
        comb += bce + lambda_e * ent;
    }

    // ---------------- one reduction for everything -> f64 partial per block
    comb = red64(comb);
    __shared__ float sm[BLOCK / 64];
    if (lane == 0) sm[wid] = comb;
    __syncthreads();
    if (threadIdx.x == 0) {
        float t0 = 0.f;
#pragma unroll
        for (int w = 0; w < BLOCK / 64; ++w) t0 += sm[w];
        partial[blockIdx.x] = (double)t0;
    }
}

__global__ void ortho_final(const double* __restrict__ partial,
                            float* __restrict__ out)
{
    double s = 0.0;
    for (int i = threadIdx.x; i < GRID; i += BLOCK) s += partial[i];
#pragma unroll
    for (int m = 1; m <= 32; m <<= 1) s += __shfl_xor(s, m, 64);
    __shared__ double sm[BLOCK / 64];
    const int lane = threadIdx.x & 63;
    const int wid  = threadIdx.x >> 6;
    if (lane == 0) sm[wid] = s;
    __syncthreads();
    if (threadIdx.x == 0) {
        double tot = 0.0;
#pragma unroll
        for (int w = 0; w < BLOCK / 64; ++w) tot += sm[w];
        out[0] = (float)(tot / (double)B_SIZE);
    }
}

extern "C" void kernel_launch(void* const* d_in, const int* in_sizes, int n_in,
                              void* d_out, int out_size, void* d_ws, size_t ws_size,
                              hipStream_t stream) {
    const float* mean_t    = (const float*)d_in[0];
    const float* mean_s    = (const float*)d_in[1];
    const float* log_std_t = (const float*)d_in[2];
    const float* log_std_s = (const float*)d_in[3];
    const float* y_zt      = (const float*)d_in[4];
    const float* s_zt      = (const float*)d_in[5];
    // d_in[6] s_zs, d_in[7] z1, d_in[8] z2: unused by the reference
    const float* target    = (const float*)d_in[9];
    const float* noise_pt  = (const float*)d_in[10];
    const float* noise_ps  = (const float*)d_in[11];
    const float* noise_et  = (const float*)d_in[12];
    const float* noise_es  = (const float*)d_in[13];
    const int*   step      = (const int*)d_in[14];

    double* partial = (double*)d_ws;   // 2048 doubles, all written every launch
    float*  out     = (float*)d_out;

    hipLaunchKernelGGL(ortho_main, dim3(GRID), dim3(BLOCK), 0, stream,
                       mean_t, mean_s, log_std_t, log_std_s,
                       y_zt, s_zt, target,
                       noise_pt, noise_ps, noise_et, noise_es, step, partial);
    hipLaunchKernelGGL(ortho_final, dim3(1), dim3(BLOCK), 0, stream, partial, out);
}

// Round 4
// 274.968 us; speedup vs baseline: 1.2981x; 1.1083x over previous
//
#include <hip/hip_runtime.h>

// OrthoLoss: scalar = BCE(y_zt,target) + lambda_od*(KL_t+KL_s) + lambda_e*Entropy(s_zt)
// B=65536, D=128. 257 MB of read-once data; ~131 MB misses to HBM.
//
// Round-4 design (R2/R3 pinned at ~104 us with both pipes idle -> MLP-starved):
//  - PERSISTENT waves: 1024 blocks = exactly 4 blocks/CU (launch_bounds(256,4)),
//    no block churn. Each wave loops 16 iterations instead of one-shot, with an
//    explicit rotating double buffer: next iteration's 4 loads are issued
//    before computing the current one -> loads stay in flight continuously.
//  - t/s stream split across blocks (bid&1): 4 arrays per wave, not 8.
//    Each wave streams 4 consecutive row-groups = 16 KB contiguous per array.
//  - Nontemporal loads (read-once data): avoids L3 thrash/dirty evictions.

#define B_SIZE 65536
#define D_SIZE 128
#define GRID   1024
#define BLOCK  256

#define L2E  1.44269504089f           // log2(e)
#define HL2E 0.72134752045f           // 0.5*log2(e)
#define SHIFT_L2E 57.7078016356f      // 40*log2(e)

typedef float vf4 __attribute__((ext_vector_type(4)));

__device__ __forceinline__ vf4 ntload(const float* p) {
    return __builtin_nontemporal_load((const vf4*)p);
}

__device__ __forceinline__ float red8(float v) {   // sum across 8-lane group
    v += __shfl_xor(v, 1, 64);
    v += __shfl_xor(v, 2, 64);
    v += __shfl_xor(v, 4, 64);
    return v;
}
__device__ __forceinline__ float red64(float v) {  // full-wave sum
#pragma unroll
    for (int m = 1; m <= 32; m <<= 1) v += __shfl_xor(v, m, 64);
    return v;
}

__global__ __launch_bounds__(BLOCK, 4) void ortho_main(
    const float* __restrict__ mean_t,   const float* __restrict__ mean_s,
    const float* __restrict__ log_std_t,const float* __restrict__ log_std_s,
    const float* __restrict__ y_zt,     const float* __restrict__ s_zt,
    const float* __restrict__ target,
    const float* __restrict__ noise_pt, const float* __restrict__ noise_ps,
    const float* __restrict__ noise_et, const float* __restrict__ noise_es,
    const int*  __restrict__ step,
    double* __restrict__ partial)
{
    const int lane = threadIdx.x & 63;
    const int wid  = threadIdx.x >> 6;          // wave in block (0..3)
    const int k    = lane & 7;                  // lane within 8-lane row group
    const int sub  = lane >> 3;                 // row within group (0..7)

    const int sflag = blockIdx.x & 1;           // 0 = t stream, 1 = s stream
    const int wave  = (blockIdx.x >> 1) * (BLOCK / 64) + wid;  // 0..2047 per stream

    const float* __restrict__ Am = sflag ? mean_s    : mean_t;
    const float* __restrict__ Al = sflag ? log_std_s : log_std_t;
    const float* __restrict__ An = sflag ? noise_es  : noise_et;
    const float* __restrict__ Ap = sflag ? noise_ps  : noise_pt;

    // prior mean: t = zeros with [13]=1 ; s = ones with [13]=0.
    // element d = j*32 + k*4 + c ; d==13 -> (j=0, k=3, c=1)
    const float pk3    = (k == 3) ? 1.0f : 0.0f;
    const float pm_def = sflag ? 1.0f : 0.0f;
    const float pm_y0  = sflag ? 1.0f - pk3 : pk3;   // c==1 slot at j==0

    // wave handles 4 consecutive row-groups (32 rows, 16 KB/array contiguous)
    const int off = (wave * 32 + sub) * D_SIZE + k * 4;   // rg adds 1024, j adds 32

    const float frac      = (float)step[0] * (1.0f / 30.0f);
    const float lambda_e  = 0.1f   * exp2f(frac);
    const float lambda_od = 0.036f * exp2f(frac * 0.13750352374993502f); // log2(1.1)

    float comb = 0.0f;

#define ELEM(SE, SP, SEP, MX, LX, NX, PX, PM)                         \
    {                                                                 \
        float e  = fmaf(exp2f((LX) * HL2E), (NX), (MX));              \
        float ex = exp2f(fmaf(e, L2E, -SHIFT_L2E));                   \
        float p  = (PM) + (PX);                                       \
        SE += ex;                                                     \
        SP += exp2f(p * L2E);                                         \
        SEP = fmaf(ex, e - p, SEP);                                   \
    }

    // software-pipelined: rotating double buffer, 4 loads in flight during compute
    vf4 bm[2], bl[2], bn[2], bp[2];
    bm[0] = ntload(Am + off); bl[0] = ntload(Al + off);
    bn[0] = ntload(An + off); bp[0] = ntload(Ap + off);

    float se = 0.f, sp = 0.f, sep = 0.f;
#pragma unroll
    for (int it = 0; it < 16; ++it) {           // it = rg*4 + j
        const int j   = it & 3;
        const int cur = it & 1, nxt = cur ^ 1;
        if (it < 15) {                          // prefetch next iteration
            const int it2 = it + 1;
            const int o2  = off + (it2 >> 2) * (8 * D_SIZE) + (it2 & 3) * 32;
            bm[nxt] = ntload(Am + o2); bl[nxt] = ntload(Al + o2);
            bn[nxt] = ntload(An + o2); bp[nxt] = ntload(Ap + o2);
        }
        if (j == 0) { se = 0.f; sp = 0.f; sep = 0.f; }
        const float pmy = (j == 0) ? pm_y0 : pm_def;
        ELEM(se, sp, sep, bm[cur].x, bl[cur].x, bn[cur].x, bp[cur].x, pm_def)
        ELEM(se, sp, sep, bm[cur].y, bl[cur].y, bn[cur].y, bp[cur].y, pmy)
        ELEM(se, sp, sep, bm[cur].z, bl[cur].z, bn[cur].z, bp[cur].z, pm_def)
        ELEM(se, sp, sep, bm[cur].w, bl[cur].w, bn[cur].w, bp[cur].w, pm_def)
        if (j == 3) {                           // row-group complete: reduce
            float rse = red8(se), rsp = red8(sp), rsep = red8(sep);
            if (k == 0)
                comb += rsep / rse - 40.0f + (__logf(rsp) - __logf(rse));
        }
    }
#undef ELEM
    comb *= lambda_od;

    // ---------------- small terms: 64 rows of BCE + entropy per block
    if (threadIdx.x < 64) {
        const int b = blockIdx.x * 64 + threadIdx.x;
        const float y = y_zt[b];
        const float t = target[b];
        const float bce = fmaxf(y, 0.f) - y * t + __logf(1.0f + exp2f(-fabsf(y) * L2E));
        const float2 s = *(const float2*)(s_zt + 2 * (size_t)b);
        const float m   = fmaxf(s.x, s.y);
        const float lse = m + __logf(exp2f((s.x - m) * L2E) + exp2f((s.y - m) * L2E));
        const float l0 = s.x - lse, l1 = s.y - lse;
        const float ent = -(exp2f(l0 * L2E) * l0 + exp2f(l1 * L2E) * l1);
        comb += bce + lambda_e * ent;
    }

    // ---------------- block reduce -> one f64 partial per block
    comb = red64(comb);
    __shared__ float sm[BLOCK / 64];
    if (lane == 0) sm[wid] = comb;
    __syncthreads();
    if (threadIdx.x == 0) {
        float t0 = 0.f;
#pragma unroll
        for (int w = 0; w < BLOCK / 64; ++w) t0 += sm[w];
        partial[blockIdx.x] = (double)t0;
    }
}

__global__ void ortho_final(const double* __restrict__ partial,
                            float* __restrict__ out)
{
    double s = 0.0;
    for (int i = threadIdx.x; i < GRID; i += BLOCK) s += partial[i];
#pragma unroll
    for (int m = 1; m <= 32; m <<= 1) s += __shfl_xor(s, m, 64);
    __shared__ double sm[BLOCK / 64];
    const int lane = threadIdx.x & 63;
    const int wid  = threadIdx.x >> 6;
    if (lane == 0) sm[wid] = s;
    __syncthreads();
    if (threadIdx.x == 0) {
        double tot = 0.0;
#pragma unroll
        for (int w = 0; w < BLOCK / 64; ++w) tot += sm[w];
        out[0] = (float)(tot / (double)B_SIZE);
    }
}

extern "C" void kernel_launch(void* const* d_in, const int* in_sizes, int n_in,
                              void* d_out, int out_size, void* d_ws, size_t ws_size,
                              hipStream_t stream) {
    const float* mean_t    = (const float*)d_in[0];
    const float* mean_s    = (const float*)d_in[1];
    const float* log_std_t = (const float*)d_in[2];
    const float* log_std_s = (const float*)d_in[3];
    const float* y_zt      = (const float*)d_in[4];
    const float* s_zt      = (const float*)d_in[5];
    // d_in[6] s_zs, d_in[7] z1, d_in[8] z2: unused by the reference
    const float* target    = (const float*)d_in[9];
    const float* noise_pt  = (const float*)d_in[10];
    const float* noise_ps  = (const float*)d_in[11];
    const float* noise_et  = (const float*)d_in[12];
    const float* noise_es  = (const float*)d_in[13];
    const int*   step      = (const int*)d_in[14];

    double* partial = (double*)d_ws;   // 1024 doubles, all written every launch
    float*  out     = (float*)d_out;

    hipLaunchKernelGGL(ortho_main, dim3(GRID), dim3(BLOCK), 0, stream,
                       mean_t, mean_s, log_std_t, log_std_s,
                       y_zt, s_zt, target,
                       noise_pt, noise_ps, noise_et, noise_es, step, partial);
    hipLaunchKernelGGL(ortho_final, dim3(1), dim3(BLOCK), 0, stream, partial, out);
}